// Round 2
// baseline (82099.451 us; speedup 1.0000x reference)
//
#include <hip/hip_runtime.h>
#include <math.h>

// ---------------------------------------------------------------------------
// SpatialTransformer forward, fp32 end-to-end.
// conv0(1x1)+BN+ReLU folded analytically (BN stats from 16x16 moment matrix),
// then 5x [conv3x3(valid)+maxpool3s2+BN+ReLU] -> LRN(128) -> GEMV(7x2048)
// -> spectral-norm scan -> affine_grid + grid_sample(reflect) * sigmoid(m).
// Conv biases cancel exactly in training-mode BN and are skipped.
// Memory plan: ws holds only the (16,128,110,110) stage-1 tensor (~94.6 MiB);
// the 2-image stage-0 activation (exactly out_size floats) and the small ping
// buffer live in d_out, which the final sample kernel fully overwrites.
// ---------------------------------------------------------------------------

#define CO_PB 4  // output channels per conv3pool block

// ---------------- util: zero a small region --------------------------------
__global__ void zero_kernel(float* __restrict__ p, int n) {
  int i = blockIdx.x * 256 + threadIdx.x;
  if (i < n) p[i] = 0.f;
}

// ---------------- moments of x: sums[16], upper-tri products[136] ----------
__global__ __launch_bounds__(256) void moment_kernel(
    const float* __restrict__ x, float* __restrict__ mom) {
  const int tid = threadIdx.x;
  int q = blockIdx.x * 256 + tid;  // 0..200703 quad index
  int n = q / 12544, pq = q - n * 12544;
  const float* xb = x + ((long)n * 16) * 50176 + pq * 4;
  float4 v4[16];
#pragma unroll
  for (int i = 0; i < 16; ++i) v4[i] = *(const float4*)(xb + (long)i * 50176);
  float accs[16];
  float accp[136];
#pragma unroll
  for (int i = 0; i < 16; ++i) accs[i] = 0.f;
#pragma unroll
  for (int k = 0; k < 136; ++k) accp[k] = 0.f;
#pragma unroll
  for (int p = 0; p < 4; ++p) {
    float v[16];
#pragma unroll
    for (int i = 0; i < 16; ++i)
      v[i] = (p == 0) ? v4[i].x : (p == 1) ? v4[i].y : (p == 2) ? v4[i].z : v4[i].w;
#pragma unroll
    for (int i = 0; i < 16; ++i) accs[i] += v[i];
    int k = 0;
#pragma unroll
    for (int i = 0; i < 16; ++i)
#pragma unroll
      for (int j = i; j < 16; ++j) { accp[k] += v[i] * v[j]; ++k; }
  }
  __shared__ float s_part[4][152];
  const int lane = tid & 63, wv = tid >> 6;
#pragma unroll
  for (int k = 0; k < 16; ++k) {
    float t = accs[k];
#pragma unroll
    for (int o = 32; o; o >>= 1) t += __shfl_down(t, o, 64);
    if (lane == 0) s_part[wv][k] = t;
  }
#pragma unroll
  for (int k = 0; k < 136; ++k) {
    float t = accp[k];
#pragma unroll
    for (int o = 32; o; o >>= 1) t += __shfl_down(t, o, 64);
    if (lane == 0) s_part[wv][16 + k] = t;
  }
  __syncthreads();
  if (tid < 152) {
    float t = s_part[0][tid] + s_part[1][tid] + s_part[2][tid] + s_part[3][tid];
    atomicAdd(&mom[tid], t);
  }
}

// ---------------- fold conv0 + BN into W' x + b' ---------------------------
__global__ void foldbn_kernel(const float* __restrict__ w0,
                              const float* __restrict__ mom,
                              const float* __restrict__ g,
                              const float* __restrict__ b,
                              float* __restrict__ Wp, float* __restrict__ bp) {
  int c = threadIdx.x;
  if (c >= 128) return;
  const float invN = 1.f / 802816.f;
  float w[16], m[16];
#pragma unroll
  for (int i = 0; i < 16; ++i) { w[i] = w0[c * 16 + i]; m[i] = mom[i] * invN; }
  float mu = 0.f;
#pragma unroll
  for (int i = 0; i < 16; ++i) mu += w[i] * m[i];
  float ey2 = 0.f;
  int k = 0;
#pragma unroll
  for (int i = 0; i < 16; ++i)
#pragma unroll
    for (int j = i; j < 16; ++j) {
      float Mij = mom[16 + k] * invN;
      ey2 += ((i == j) ? 1.f : 2.f) * w[i] * w[j] * Mij;
      ++k;
    }
  float var = ey2 - mu * mu;
  float al = g[c] * rsqrtf(var + 1e-5f);
#pragma unroll
  for (int i = 0; i < 16; ++i) Wp[c * 16 + i] = al * w[i];
  bp[c] = b[c] - al * mu;
}

// ---------------- stage 0 folded: act = relu(W' x + b'), 2 images ----------
__global__ __launch_bounds__(256) void conv0act_kernel(
    const float* __restrict__ x, const float* __restrict__ Wp,
    const float* __restrict__ bp, float* __restrict__ act, int n_base) {
  __shared__ float sw[512];
  __shared__ float sb[32];
  const int tid = threadIdx.x;
  const int co0 = blockIdx.y * 32;
  for (int e = tid; e < 512; e += 256) sw[e] = Wp[co0 * 16 + e];
  if (tid < 32) sb[tid] = bp[co0 + tid];
  __syncthreads();
  const int q = blockIdx.x * 256 + tid;  // 0..12543 quad within image
  const int nloc = blockIdx.z;
  const float* xb = x + ((long)(n_base + nloc) * 16) * 50176 + q * 4;
  float4 v4[16];
#pragma unroll
  for (int i = 0; i < 16; ++i) v4[i] = *(const float4*)(xb + (long)i * 50176);
  float* ob = act + ((long)nloc * 128) * 50176 + q * 4;
  for (int u = 0; u < 32; ++u) {
    float bb = sb[u];
    float4 a = make_float4(bb, bb, bb, bb);
#pragma unroll
    for (int i = 0; i < 16; ++i) {
      float w = sw[u * 16 + i];
      a.x += w * v4[i].x; a.y += w * v4[i].y;
      a.z += w * v4[i].z; a.w += w * v4[i].w;
    }
    a.x = fmaxf(a.x, 0.f); a.y = fmaxf(a.y, 0.f);
    a.z = fmaxf(a.z, 0.f); a.w = fmaxf(a.w, 0.f);
    *(float4*)(ob + (long)(co0 + u) * 50176) = a;
  }
}

// ---------------- per-channel BN statistics (sum, sumsq) -------------------
__global__ __launch_bounds__(256) void stats_kernel(
    const float* __restrict__ buf, float* __restrict__ stats, int P2) {
  const int c = blockIdx.x;
  const int n = blockIdx.y;
  const int tid = threadIdx.x;
  const float* b = buf + ((long)n * 128 + c) * P2;
  float s = 0.f, q = 0.f;
  for (int i = tid; i < P2; i += 256) {
    float v = b[i];
    s += v; q += v * v;
  }
  __shared__ float rs[256], rq[256];
  rs[tid] = s; rq[tid] = q;
  __syncthreads();
  for (int off = 128; off; off >>= 1) {
    if (tid < off) { rs[tid] += rs[tid + off]; rq[tid] += rq[tid + off]; }
    __syncthreads();
  }
  if (tid == 0) {
    atomicAdd(&stats[c], rs[0]);
    atomicAdd(&stats[128 + c], rq[0]);
  }
}

// ---------------- apply BN + ReLU in place ---------------------------------
__global__ __launch_bounds__(256) void bnrelu_kernel(
    float* __restrict__ buf, const float* __restrict__ stats,
    const float* __restrict__ g, const float* __restrict__ b,
    int P2, float invM, long total) {
  long i = (long)blockIdx.x * 256 + threadIdx.x;
  if (i >= total) return;
  int c = (int)((i / P2) & 127);
  float mu = stats[c] * invM;
  float var = stats[128 + c] * invM - mu * mu;
  float al = g[c] * rsqrtf(var + 1e-5f);
  float v = buf[i];
  buf[i] = fmaxf(al * (v - mu) + b[c], 0.f);
}

// ---------------- fused conv3x3(valid, no bias) + maxpool3s2 ---------------
// grid: x = tiles^2 (16x16 pooled tiles), y = 32 co-groups, z = images
// Input indexed by local image blockIdx.z; output by n_base+blockIdx.z.
__global__ __launch_bounds__(256, 2) void conv3pool_kernel(
    const float* __restrict__ in, const float* __restrict__ wt,
    float* __restrict__ out, int Sin, int Pout, int n_base) {
  const int tid = threadIdx.x;
  const int tilesX = (Pout + 15) >> 4;
  const int ty = blockIdx.x / tilesX, tx = blockIdx.x - ty * tilesX;
  const int co0 = blockIdx.y * CO_PB;
  const int nloc = blockIdx.z;
  const int py0 = ty * 16, px0 = tx * 16;
  const int iy0 = py0 * 2, ix0 = px0 * 2;

  __shared__ float s_w[CO_PB * 1152];  // (co_local, ci, 9)
  __shared__ float s_in[4 * 1296];     // 4 ci x 36x36 input tile

  for (int e = tid; e < CO_PB * 1152; e += 256)
    s_w[e] = wt[(long)co0 * 1152 + e];

  const bool two = (tid < 33);  // 289 patches; threads 0..32 own a second
  float acc[2][CO_PB][4];
#pragma unroll
  for (int pp = 0; pp < 2; ++pp)
#pragma unroll
    for (int u = 0; u < CO_PB; ++u)
#pragma unroll
      for (int k = 0; k < 4; ++k) acc[pp][u][k] = 0.f;

  const long S2 = (long)Sin * Sin;
  const long inbase = ((long)nloc * 128) * S2;

  __syncthreads();
  for (int ci0 = 0; ci0 < 128; ci0 += 4) {
    __syncthreads();
    for (int e = tid; e < 4 * 1296; e += 256) {
      int cil = e / 1296;
      int rem = e - cil * 1296;
      int r = rem / 36, cc = rem - r * 36;
      int gy = iy0 + r; if (gy > Sin - 1) gy = Sin - 1;
      int gx = ix0 + cc; if (gx > Sin - 1) gx = Sin - 1;
      s_in[e] = in[inbase + (long)(ci0 + cil) * S2 + (long)gy * Sin + gx];
    }
    __syncthreads();
    for (int cil = 0; cil < 4; ++cil) {
      float wreg[CO_PB][9];
#pragma unroll
      for (int u = 0; u < CO_PB; ++u)
#pragma unroll
        for (int k = 0; k < 9; ++k)
          wreg[u][k] = s_w[u * 1152 + (ci0 + cil) * 9 + k];
      const float* sbase = &s_in[cil * 1296];
#pragma unroll
      for (int pp = 0; pp < 2; ++pp) {
        if (pp == 1 && !two) continue;
        int pidx = tid + pp * 256;  // < 289
        int pi = pidx / 17, pj = pidx - pi * 17;
        const float* ip = sbase + pi * 72 + pj * 2;
        float iv[16];
#pragma unroll
        for (int r = 0; r < 4; ++r)
#pragma unroll
          for (int cc2 = 0; cc2 < 4; ++cc2)
            iv[r * 4 + cc2] = ip[r * 36 + cc2];
#pragma unroll
        for (int u = 0; u < CO_PB; ++u) {
          float a00 = 0.f, a01 = 0.f, a10 = 0.f, a11 = 0.f;
#pragma unroll
          for (int ky = 0; ky < 3; ++ky)
#pragma unroll
            for (int kx = 0; kx < 3; ++kx) {
              float w = wreg[u][ky * 3 + kx];
              a00 += w * iv[ky * 4 + kx];
              a01 += w * iv[ky * 4 + kx + 1];
              a10 += w * iv[(ky + 1) * 4 + kx];
              a11 += w * iv[(ky + 1) * 4 + kx + 1];
            }
          acc[pp][u][0] += a00; acc[pp][u][1] += a01;
          acc[pp][u][2] += a10; acc[pp][u][3] += a11;
        }
      }
    }
  }

  // pooling via LDS staging of the 34x34 conv tile, one co at a time
  float* s_conv = s_in;
  const int py = tid >> 4, px = tid & 15;
  const int gpy = py0 + py, gpx = px0 + px;
  const bool wvalid = (gpy < Pout) && (gpx < Pout);
  for (int u = 0; u < CO_PB; ++u) {
    __syncthreads();
#pragma unroll
    for (int pp = 0; pp < 2; ++pp) {
      if (pp == 1 && !two) continue;
      int pidx = tid + pp * 256;
      int pi = pidx / 17, pj = pidx - pi * 17;
      float* cp = s_conv + pi * 68 + pj * 2;
      cp[0] = acc[pp][u][0]; cp[1] = acc[pp][u][1];
      cp[34] = acc[pp][u][2]; cp[35] = acc[pp][u][3];
    }
    __syncthreads();
    if (wvalid) {
      const float* cp = s_conv + (2 * py) * 34 + 2 * px;
      float mx = cp[0];
#pragma unroll
      for (int dy = 0; dy < 3; ++dy)
#pragma unroll
        for (int dx = 0; dx < 3; ++dx)
          mx = fmaxf(mx, cp[dy * 34 + dx]);
      out[(((long)(n_base + nloc) * 128 + (co0 + u)) * Pout + gpy) * Pout + gpx] = mx;
    }
  }
}

// ---------------- LRN, size = 128 over the channel axis --------------------
__global__ __launch_bounds__(128) void lrn_kernel(float* __restrict__ buf) {
  const int n = blockIdx.x;
  const int c = threadIdx.x;
  __shared__ float sq[128];
  float* b = buf + (long)n * 2048;
  for (int p = 0; p < 16; ++p) {
    float v = b[c * 16 + p];
    sq[c] = v * v;
    __syncthreads();
    int lo = c - 64 < 0 ? 0 : c - 64;
    int hi = c + 63 > 127 ? 127 : c + 63;
    float win = 0.f;
    for (int j = lo; j <= hi; ++j) win += sq[j];
    b[c * 16 + p] = v * powf(1.f + (1e-4f / 128.f) * win, -0.75f);
    __syncthreads();
  }
}

// ---------------- regression head: reg = xs @ Wr.T + br --------------------
__global__ __launch_bounds__(256) void gemv_kernel(
    const float* __restrict__ xs, const float* __restrict__ Wr,
    const float* __restrict__ br, float* __restrict__ reg) {
  const int n = blockIdx.x;
  const int tid = threadIdx.x;
  float a[7] = {0.f, 0.f, 0.f, 0.f, 0.f, 0.f, 0.f};
  for (int e = tid; e < 2048; e += 256) {
    float v = xs[(long)n * 2048 + e];
#pragma unroll
    for (int j = 0; j < 7; ++j) a[j] += v * Wr[j * 2048 + e];
  }
  __shared__ float red[256];
  for (int j = 0; j < 7; ++j) {
    red[tid] = a[j];
    __syncthreads();
    for (int off = 128; off; off >>= 1) {
      if (tid < off) red[tid] += red[tid + off];
      __syncthreads();
    }
    if (tid == 0) reg[n * 7 + j] = red[0] + br[j];
    __syncthreads();
  }
}

// ---------------- spectral norm (sequential scan over batch) ---------------
__global__ void sn_kernel(const float* __restrict__ reg,
                          const float* __restrict__ u0g,
                          const float* __restrict__ v0g,
                          float* __restrict__ theta, float* __restrict__ m) {
  if (threadIdx.x != 0 || blockIdx.x != 0) return;
  float u[2] = {u0g[0], u0g[1]};
  float v[3] = {v0g[0], v0g[1], v0g[2]};
  for (int n = 0; n < 16; ++n) {
    const float* W = reg + n * 7;
    for (int it = 0; it < 4; ++it) {
      float v0n = W[0] * u[0] + W[3] * u[1];
      float v1n = W[1] * u[0] + W[4] * u[1];
      float v2n = W[2] * u[0] + W[5] * u[1];
      float nv = sqrtf(v0n * v0n + v1n * v1n + v2n * v2n);
      nv = fmaxf(nv, 1e-12f);
      v[0] = v0n / nv; v[1] = v1n / nv; v[2] = v2n / nv;
      float u0n = W[0] * v[0] + W[1] * v[1] + W[2] * v[2];
      float u1n = W[3] * v[0] + W[4] * v[1] + W[5] * v[2];
      float nu = sqrtf(u0n * u0n + u1n * u1n);
      nu = fmaxf(nu, 1e-12f);
      u[0] = u0n / nu; u[1] = u1n / nu;
    }
    float Wv0 = W[0] * v[0] + W[1] * v[1] + W[2] * v[2];
    float Wv1 = W[3] * v[0] + W[4] * v[1] + W[5] * v[2];
    float sigma = u[0] * Wv0 + u[1] * Wv1;
    for (int k = 0; k < 6; ++k) theta[n * 6 + k] = W[k] / sigma;
    m[n] = 1.f / (1.f + expf(-W[6]));
  }
}

// ---------------- affine grid + reflect grid_sample + mask scale -----------
__device__ __forceinline__ float reflectf(float x, float size) {
  x = fabsf(x + 0.5f);
  x = fmodf(x, 2.f * size);
  if (x > size) x = 2.f * size - x;
  x -= 0.5f;
  return fminf(fmaxf(x, 0.f), size - 1.f);
}

__global__ __launch_bounds__(256) void sample_kernel(
    const float* __restrict__ x, const float* __restrict__ theta,
    const float* __restrict__ m, float* __restrict__ out) {
  long i = (long)blockIdx.x * 256 + threadIdx.x;
  if (i >= 12845056L) return;
  int w = (int)(i % 224);
  long t = i / 224;
  int h = (int)(t % 224); t /= 224;
  int c = (int)(t % 16);
  int n = (int)(t / 16);
  const float* th = theta + n * 6;
  float xn = (2 * w + 1) * (1.f / 224.f) - 1.f;
  float yn = (2 * h + 1) * (1.f / 224.f) - 1.f;
  float gx = th[0] * xn + th[1] * yn + th[2];
  float gy = th[3] * xn + th[4] * yn + th[5];
  float ix = reflectf(((gx + 1.f) * 224.f - 1.f) * 0.5f, 224.f);
  float iy = reflectf(((gy + 1.f) * 224.f - 1.f) * 0.5f, 224.f);
  float x0 = floorf(ix), y0 = floorf(iy);
  float wx = ix - x0, wy = iy - y0;
  int x0i = (int)x0; if (x0i < 0) x0i = 0; if (x0i > 223) x0i = 223;
  int y0i = (int)y0; if (y0i < 0) y0i = 0; if (y0i > 223) y0i = 223;
  int x1i = (int)x0 + 1; if (x1i < 0) x1i = 0; if (x1i > 223) x1i = 223;
  int y1i = (int)y0 + 1; if (y1i < 0) y1i = 0; if (y1i > 223) y1i = 223;
  const float* im = x + ((long)n * 16 + c) * 50176;
  float v00 = im[y0i * 224 + x0i], v01 = im[y0i * 224 + x1i];
  float v10 = im[y1i * 224 + x0i], v11 = im[y1i * 224 + x1i];
  float val = v00 * (1.f - wx) * (1.f - wy) + v01 * wx * (1.f - wy) +
              v10 * (1.f - wx) * wy + v11 * wx * wy;
  out[i] = val * m[n];
}

// ---------------------------------------------------------------------------
extern "C" void kernel_launch(void* const* d_in, const int* in_sizes, int n_in,
                              void* d_out, int out_size, void* d_ws,
                              size_t ws_size, hipStream_t stream) {
  const float* x       = (const float*)d_in[0];
  const float* conv0_w = (const float*)d_in[1];
  // d_in[2] conv0_b: cancels in BN, unused
  const float* convs_w = (const float*)d_in[3];
  // d_in[4] convs_b: cancels in BN, unused
  const float* bn_g = (const float*)d_in[5];
  const float* bn_b = (const float*)d_in[6];
  const float* Wr   = (const float*)d_in[7];
  const float* br   = (const float*)d_in[8];
  const float* u0   = (const float*)d_in[9];
  const float* v0   = (const float*)d_in[10];
  float* out = (float*)d_out;
  float* ws  = (float*)d_ws;

  // ws layout (floats): total 24,783,616 (~94.6 MiB)
  float* bufB   = ws;                  // 24,780,800 (16,128,110,110)
  float* stats  = ws + 24780800L;      // 256
  float* mom    = stats + 256;         // 152 (pad 160)
  float* Wp     = mom + 160;           // 2048
  float* bp     = Wp + 2048;           // 128
  float* regb   = bp + 128;            // 112
  float* thetab = regb + 112;          // 96
  float* mb     = thetab + 96;         // 16

  // d_out scratch: tempAct = 2 images x (128,224,224) = 12,845,056 floats
  // (exactly out_size); bufC (<=5,750,272 floats) reuses d_out after stage 1.
  float* tempAct = out;
  float* bufC    = out;

  // ---- stage-0 BN stats analytically from x moments; fold into W', b' ----
  zero_kernel<<<2, 256, 0, stream>>>(stats, 416);  // stats + mom
  moment_kernel<<<784, 256, 0, stream>>>(x, mom);
  foldbn_kernel<<<1, 128, 0, stream>>>(conv0_w, mom, bn_g, bn_b, Wp, bp);

  // ---- stage 0+1 in 8 rounds of 2 images ----
  for (int r = 0; r < 8; ++r) {
    conv0act_kernel<<<dim3(49, 4, 2), 256, 0, stream>>>(x, Wp, bp, tempAct,
                                                        2 * r);
    conv3pool_kernel<<<dim3(49, 32, 2), 256, 0, stream>>>(
        tempAct, convs_w, bufB, 224, 110, 2 * r);
  }
  zero_kernel<<<1, 256, 0, stream>>>(stats, 256);
  stats_kernel<<<dim3(128, 16), 256, 0, stream>>>(bufB, stats, 12100);
  {
    long total = 16L * 128 * 12100;
    bnrelu_kernel<<<(int)((total + 255) / 256), 256, 0, stream>>>(
        bufB, stats, bn_g + 128, bn_b + 128, 12100, 1.f / (16.f * 12100.f),
        total);
  }

  // ---- stages 2..5: ping-pong bufB <-> bufC(d_out) ----
  const int Sins[4]  = {110, 53, 25, 11};
  const int Pouts[4] = {53, 25, 11, 4};
  for (int s = 0; s < 4; ++s) {
    float* ib = (s % 2 == 0) ? bufB : bufC;
    float* ob = (s % 2 == 0) ? bufC : bufB;
    int Sin = Sins[s], Pout = Pouts[s];
    int tiles = (Pout + 15) / 16;
    conv3pool_kernel<<<dim3(tiles * tiles, 32, 16), 256, 0, stream>>>(
        ib, convs_w + (long)(s + 1) * 128 * 128 * 9, ob, Sin, Pout, 0);
    zero_kernel<<<1, 256, 0, stream>>>(stats, 256);
    int P2 = Pout * Pout;
    stats_kernel<<<dim3(128, 16), 256, 0, stream>>>(ob, stats, P2);
    long total = 16L * 128 * P2;
    bnrelu_kernel<<<(int)((total + 255) / 256), 256, 0, stream>>>(
        ob, stats, bn_g + (s + 2) * 128, bn_b + (s + 2) * 128, P2,
        1.f / (16.f * P2), total);
  }

  // ---- tail: LRN -> GEMV -> spectral norm -> sample (overwrites d_out) ----
  lrn_kernel<<<16, 128, 0, stream>>>(bufB);
  gemv_kernel<<<16, 256, 0, stream>>>(bufB, Wr, br, regb);
  sn_kernel<<<1, 1, 0, stream>>>(regb, u0, v0, thetab, mb);
  sample_kernel<<<50176, 256, 0, stream>>>(x, thetab, mb, out);
}

// Round 3
// 28409.821 us; speedup vs baseline: 2.8898x; 2.8898x over previous
//
#include <hip/hip_runtime.h>
#include <math.h>

// ---------------------------------------------------------------------------
// SpatialTransformer forward, fp32 end-to-end.
// conv0(1x1)+BN+ReLU folded analytically (BN stats from 16x16 moment matrix),
// then 5x [conv3x3(valid)+maxpool3s2+BN+ReLU] -> LRN(128) -> GEMV(7x2048)
// -> spectral-norm scan -> affine_grid + grid_sample(reflect) * sigmoid(m).
// Conv biases cancel exactly in training-mode BN and are skipped.
// R3: conv3pool de-spilled — weights via uniform (scalar) global loads,
// CO_PB=8, padded LDS strides (37/35), launch_bounds(256,4).
// ---------------------------------------------------------------------------

#define CO_PB 8  // output channels per conv3pool block

// ---------------- util: zero a small region --------------------------------
__global__ void zero_kernel(float* __restrict__ p, int n) {
  int i = blockIdx.x * 256 + threadIdx.x;
  if (i < n) p[i] = 0.f;
}

// ---------------- moments of x: sums[16], upper-tri products[136] ----------
__global__ __launch_bounds__(256) void moment_kernel(
    const float* __restrict__ x, float* __restrict__ mom) {
  const int tid = threadIdx.x;
  int q = blockIdx.x * 256 + tid;  // 0..200703 quad index
  int n = q / 12544, pq = q - n * 12544;
  const float* xb = x + ((long)n * 16) * 50176 + pq * 4;
  float4 v4[16];
#pragma unroll
  for (int i = 0; i < 16; ++i) v4[i] = *(const float4*)(xb + (long)i * 50176);
  float accs[16];
  float accp[136];
#pragma unroll
  for (int i = 0; i < 16; ++i) accs[i] = 0.f;
#pragma unroll
  for (int k = 0; k < 136; ++k) accp[k] = 0.f;
#pragma unroll
  for (int p = 0; p < 4; ++p) {
    float v[16];
#pragma unroll
    for (int i = 0; i < 16; ++i)
      v[i] = (p == 0) ? v4[i].x : (p == 1) ? v4[i].y : (p == 2) ? v4[i].z : v4[i].w;
#pragma unroll
    for (int i = 0; i < 16; ++i) accs[i] += v[i];
    int k = 0;
#pragma unroll
    for (int i = 0; i < 16; ++i)
#pragma unroll
      for (int j = i; j < 16; ++j) { accp[k] += v[i] * v[j]; ++k; }
  }
  __shared__ float s_part[4][152];
  const int lane = tid & 63, wv = tid >> 6;
#pragma unroll
  for (int k = 0; k < 16; ++k) {
    float t = accs[k];
#pragma unroll
    for (int o = 32; o; o >>= 1) t += __shfl_down(t, o, 64);
    if (lane == 0) s_part[wv][k] = t;
  }
#pragma unroll
  for (int k = 0; k < 136; ++k) {
    float t = accp[k];
#pragma unroll
    for (int o = 32; o; o >>= 1) t += __shfl_down(t, o, 64);
    if (lane == 0) s_part[wv][16 + k] = t;
  }
  __syncthreads();
  if (tid < 152) {
    float t = s_part[0][tid] + s_part[1][tid] + s_part[2][tid] + s_part[3][tid];
    atomicAdd(&mom[tid], t);
  }
}

// ---------------- fold conv0 + BN into W' x + b' ---------------------------
__global__ void foldbn_kernel(const float* __restrict__ w0,
                              const float* __restrict__ mom,
                              const float* __restrict__ g,
                              const float* __restrict__ b,
                              float* __restrict__ Wp, float* __restrict__ bp) {
  int c = threadIdx.x;
  if (c >= 128) return;
  const float invN = 1.f / 802816.f;
  float w[16], m[16];
#pragma unroll
  for (int i = 0; i < 16; ++i) { w[i] = w0[c * 16 + i]; m[i] = mom[i] * invN; }
  float mu = 0.f;
#pragma unroll
  for (int i = 0; i < 16; ++i) mu += w[i] * m[i];
  float ey2 = 0.f;
  int k = 0;
#pragma unroll
  for (int i = 0; i < 16; ++i)
#pragma unroll
    for (int j = i; j < 16; ++j) {
      float Mij = mom[16 + k] * invN;
      ey2 += ((i == j) ? 1.f : 2.f) * w[i] * w[j] * Mij;
      ++k;
    }
  float var = ey2 - mu * mu;
  float al = g[c] * rsqrtf(var + 1e-5f);
#pragma unroll
  for (int i = 0; i < 16; ++i) Wp[c * 16 + i] = al * w[i];
  bp[c] = b[c] - al * mu;
}

// ---------------- stage 0 folded: act = relu(W' x + b'), 2 images ----------
__global__ __launch_bounds__(256) void conv0act_kernel(
    const float* __restrict__ x, const float* __restrict__ Wp,
    const float* __restrict__ bp, float* __restrict__ act, int n_base) {
  __shared__ float sw[512];
  __shared__ float sb[32];
  const int tid = threadIdx.x;
  const int co0 = blockIdx.y * 32;
  for (int e = tid; e < 512; e += 256) sw[e] = Wp[co0 * 16 + e];
  if (tid < 32) sb[tid] = bp[co0 + tid];
  __syncthreads();
  const int q = blockIdx.x * 256 + tid;  // 0..12543 quad within image
  const int nloc = blockIdx.z;
  const float* xb = x + ((long)(n_base + nloc) * 16) * 50176 + q * 4;
  float4 v4[16];
#pragma unroll
  for (int i = 0; i < 16; ++i) v4[i] = *(const float4*)(xb + (long)i * 50176);
  float* ob = act + ((long)nloc * 128) * 50176 + q * 4;
  for (int u = 0; u < 32; ++u) {
    float bb = sb[u];
    float4 a = make_float4(bb, bb, bb, bb);
#pragma unroll
    for (int i = 0; i < 16; ++i) {
      float w = sw[u * 16 + i];
      a.x += w * v4[i].x; a.y += w * v4[i].y;
      a.z += w * v4[i].z; a.w += w * v4[i].w;
    }
    a.x = fmaxf(a.x, 0.f); a.y = fmaxf(a.y, 0.f);
    a.z = fmaxf(a.z, 0.f); a.w = fmaxf(a.w, 0.f);
    *(float4*)(ob + (long)(co0 + u) * 50176) = a;
  }
}

// ---------------- per-channel BN statistics (sum, sumsq) -------------------
__global__ __launch_bounds__(256) void stats_kernel(
    const float* __restrict__ buf, float* __restrict__ stats, int P2) {
  const int c = blockIdx.x;
  const int n = blockIdx.y;
  const int tid = threadIdx.x;
  const float* b = buf + ((long)n * 128 + c) * P2;
  float s = 0.f, q = 0.f;
  for (int i = tid; i < P2; i += 256) {
    float v = b[i];
    s += v; q += v * v;
  }
  __shared__ float rs[256], rq[256];
  rs[tid] = s; rq[tid] = q;
  __syncthreads();
  for (int off = 128; off; off >>= 1) {
    if (tid < off) { rs[tid] += rs[tid + off]; rq[tid] += rq[tid + off]; }
    __syncthreads();
  }
  if (tid == 0) {
    atomicAdd(&stats[c], rs[0]);
    atomicAdd(&stats[128 + c], rq[0]);
  }
}

// ---------------- apply BN + ReLU in place ---------------------------------
__global__ __launch_bounds__(256) void bnrelu_kernel(
    float* __restrict__ buf, const float* __restrict__ stats,
    const float* __restrict__ g, const float* __restrict__ b,
    int P2, float invM, long total) {
  long i = (long)blockIdx.x * 256 + threadIdx.x;
  if (i >= total) return;
  int c = (int)((i / P2) & 127);
  float mu = stats[c] * invM;
  float var = stats[128 + c] * invM - mu * mu;
  float al = g[c] * rsqrtf(var + 1e-5f);
  float v = buf[i];
  buf[i] = fmaxf(al * (v - mu) + b[c], 0.f);
}

// ---------------- fused conv3x3(valid, no bias) + maxpool3s2 ---------------
// grid: x = tiles^2 (16x16 pooled tiles), y = 16 co-groups (CO_PB=8),
// z = images. Weights read via block-uniform addresses -> scalar loads (no
// VGPR/LDS cost). LDS: 4ci x 36-row x stride-37 tile (21.3 KB).
__global__ __launch_bounds__(256, 4) void conv3pool_kernel(
    const float* __restrict__ in, const float* __restrict__ wt,
    float* __restrict__ out, int Sin, int Pout, int n_base) {
  const int tid = threadIdx.x;
  const int tilesX = (Pout + 15) >> 4;
  const int ty = blockIdx.x / tilesX, tx = blockIdx.x - ty * tilesX;
  const int co0 = blockIdx.y * CO_PB;
  const int nloc = blockIdx.z;
  const int py0 = ty * 16, px0 = tx * 16;
  const int iy0 = py0 * 2, ix0 = px0 * 2;

  __shared__ float s_in[4 * 1332];  // 4 ci x (36 rows x stride 37)

  const bool two = (tid < 33);  // 289 patches; threads 0..32 own a second
  float acc[2][CO_PB][4];
#pragma unroll
  for (int pp = 0; pp < 2; ++pp)
#pragma unroll
    for (int u = 0; u < CO_PB; ++u)
#pragma unroll
      for (int k = 0; k < 4; ++k) acc[pp][u][k] = 0.f;

  const long S2 = (long)Sin * Sin;
  const long inbase = ((long)nloc * 128) * S2;

  for (int ci0 = 0; ci0 < 128; ci0 += 4) {
    __syncthreads();  // previous iteration's s_in readers done
    for (int e = tid; e < 4 * 1296; e += 256) {
      int cil = e / 1296;
      int rem = e - cil * 1296;
      int r = rem / 36, cc = rem - r * 36;
      int gy = iy0 + r; if (gy > Sin - 1) gy = Sin - 1;
      int gx = ix0 + cc; if (gx > Sin - 1) gx = Sin - 1;
      s_in[cil * 1332 + r * 37 + cc] =
          in[inbase + (long)(ci0 + cil) * S2 + (long)gy * Sin + gx];
    }
    __syncthreads();
#pragma unroll
    for (int cil = 0; cil < 4; ++cil) {
      const float* sbase = &s_in[cil * 1332];
#pragma unroll
      for (int pp = 0; pp < 2; ++pp) {
        if (pp == 1 && !two) continue;
        int pidx = tid + pp * 256;  // < 289
        int pi = pidx / 17, pj = pidx - pi * 17;
        const float* ip = sbase + pi * 74 + pj * 2;
        float iv[16];
#pragma unroll
        for (int r = 0; r < 4; ++r)
#pragma unroll
          for (int cc2 = 0; cc2 < 4; ++cc2)
            iv[r * 4 + cc2] = ip[r * 37 + cc2];
#pragma unroll
        for (int u = 0; u < CO_PB; ++u) {
          // block-uniform address -> compiler scalarizes to s_load (SGPRs)
          const float* wp = wt + ((long)(co0 + u) * 128 + (ci0 + cil)) * 9;
#pragma unroll
          for (int ky = 0; ky < 3; ++ky)
#pragma unroll
            for (int kx = 0; kx < 3; ++kx) {
              float w = wp[ky * 3 + kx];
              acc[pp][u][0] += w * iv[ky * 4 + kx];
              acc[pp][u][1] += w * iv[ky * 4 + kx + 1];
              acc[pp][u][2] += w * iv[(ky + 1) * 4 + kx];
              acc[pp][u][3] += w * iv[(ky + 1) * 4 + kx + 1];
            }
        }
      }
    }
  }

  // pooling via LDS staging of the 34x34 conv tile (stride 35), per co
  float* s_conv = s_in;
  const int py = tid >> 4, px = tid & 15;
  const int gpy = py0 + py, gpx = px0 + px;
  const bool wvalid = (gpy < Pout) && (gpx < Pout);
  for (int u = 0; u < CO_PB; ++u) {
    __syncthreads();
#pragma unroll
    for (int pp = 0; pp < 2; ++pp) {
      if (pp == 1 && !two) continue;
      int pidx = tid + pp * 256;
      int pi = pidx / 17, pj = pidx - pi * 17;
      float* cp = s_conv + pi * 70 + pj * 2;
      cp[0] = acc[pp][u][0]; cp[1] = acc[pp][u][1];
      cp[35] = acc[pp][u][2]; cp[36] = acc[pp][u][3];
    }
    __syncthreads();
    if (wvalid) {
      const float* cp = s_conv + (2 * py) * 35 + 2 * px;
      float mx = cp[0];
#pragma unroll
      for (int dy = 0; dy < 3; ++dy)
#pragma unroll
        for (int dx = 0; dx < 3; ++dx)
          mx = fmaxf(mx, cp[dy * 35 + dx]);
      out[(((long)(n_base + nloc) * 128 + (co0 + u)) * Pout + gpy) * Pout + gpx] = mx;
    }
  }
}

// ---------------- LRN, size = 128 over the channel axis --------------------
__global__ __launch_bounds__(128) void lrn_kernel(float* __restrict__ buf) {
  const int n = blockIdx.x;
  const int c = threadIdx.x;
  __shared__ float sq[128];
  float* b = buf + (long)n * 2048;
  for (int p = 0; p < 16; ++p) {
    float v = b[c * 16 + p];
    sq[c] = v * v;
    __syncthreads();
    int lo = c - 64 < 0 ? 0 : c - 64;
    int hi = c + 63 > 127 ? 127 : c + 63;
    float win = 0.f;
    for (int j = lo; j <= hi; ++j) win += sq[j];
    b[c * 16 + p] = v * powf(1.f + (1e-4f / 128.f) * win, -0.75f);
    __syncthreads();
  }
}

// ---------------- regression head: reg = xs @ Wr.T + br --------------------
__global__ __launch_bounds__(256) void gemv_kernel(
    const float* __restrict__ xs, const float* __restrict__ Wr,
    const float* __restrict__ br, float* __restrict__ reg) {
  const int n = blockIdx.x;
  const int tid = threadIdx.x;
  float a[7] = {0.f, 0.f, 0.f, 0.f, 0.f, 0.f, 0.f};
  for (int e = tid; e < 2048; e += 256) {
    float v = xs[(long)n * 2048 + e];
#pragma unroll
    for (int j = 0; j < 7; ++j) a[j] += v * Wr[j * 2048 + e];
  }
  __shared__ float red[256];
  for (int j = 0; j < 7; ++j) {
    red[tid] = a[j];
    __syncthreads();
    for (int off = 128; off; off >>= 1) {
      if (tid < off) red[tid] += red[tid + off];
      __syncthreads();
    }
    if (tid == 0) reg[n * 7 + j] = red[0] + br[j];
    __syncthreads();
  }
}

// ---------------- spectral norm (sequential scan over batch) ---------------
__global__ void sn_kernel(const float* __restrict__ reg,
                          const float* __restrict__ u0g,
                          const float* __restrict__ v0g,
                          float* __restrict__ theta, float* __restrict__ m) {
  if (threadIdx.x != 0 || blockIdx.x != 0) return;
  float u[2] = {u0g[0], u0g[1]};
  float v[3] = {v0g[0], v0g[1], v0g[2]};
  for (int n = 0; n < 16; ++n) {
    const float* W = reg + n * 7;
    for (int it = 0; it < 4; ++it) {
      float v0n = W[0] * u[0] + W[3] * u[1];
      float v1n = W[1] * u[0] + W[4] * u[1];
      float v2n = W[2] * u[0] + W[5] * u[1];
      float nv = sqrtf(v0n * v0n + v1n * v1n + v2n * v2n);
      nv = fmaxf(nv, 1e-12f);
      v[0] = v0n / nv; v[1] = v1n / nv; v[2] = v2n / nv;
      float u0n = W[0] * v[0] + W[1] * v[1] + W[2] * v[2];
      float u1n = W[3] * v[0] + W[4] * v[1] + W[5] * v[2];
      float nu = sqrtf(u0n * u0n + u1n * u1n);
      nu = fmaxf(nu, 1e-12f);
      u[0] = u0n / nu; u[1] = u1n / nu;
    }
    float Wv0 = W[0] * v[0] + W[1] * v[1] + W[2] * v[2];
    float Wv1 = W[3] * v[0] + W[4] * v[1] + W[5] * v[2];
    float sigma = u[0] * Wv0 + u[1] * Wv1;
    for (int k = 0; k < 6; ++k) theta[n * 6 + k] = W[k] / sigma;
    m[n] = 1.f / (1.f + expf(-W[6]));
  }
}

// ---------------- affine grid + reflect grid_sample + mask scale -----------
__device__ __forceinline__ float reflectf(float x, float size) {
  x = fabsf(x + 0.5f);
  x = fmodf(x, 2.f * size);
  if (x > size) x = 2.f * size - x;
  x -= 0.5f;
  return fminf(fmaxf(x, 0.f), size - 1.f);
}

__global__ __launch_bounds__(256) void sample_kernel(
    const float* __restrict__ x, const float* __restrict__ theta,
    const float* __restrict__ m, float* __restrict__ out) {
  long i = (long)blockIdx.x * 256 + threadIdx.x;
  if (i >= 12845056L) return;
  int w = (int)(i % 224);
  long t = i / 224;
  int h = (int)(t % 224); t /= 224;
  int c = (int)(t % 16);
  int n = (int)(t / 16);
  const float* th = theta + n * 6;
  float xn = (2 * w + 1) * (1.f / 224.f) - 1.f;
  float yn = (2 * h + 1) * (1.f / 224.f) - 1.f;
  float gx = th[0] * xn + th[1] * yn + th[2];
  float gy = th[3] * xn + th[4] * yn + th[5];
  float ix = reflectf(((gx + 1.f) * 224.f - 1.f) * 0.5f, 224.f);
  float iy = reflectf(((gy + 1.f) * 224.f - 1.f) * 0.5f, 224.f);
  float x0 = floorf(ix), y0 = floorf(iy);
  float wx = ix - x0, wy = iy - y0;
  int x0i = (int)x0; if (x0i < 0) x0i = 0; if (x0i > 223) x0i = 223;
  int y0i = (int)y0; if (y0i < 0) y0i = 0; if (y0i > 223) y0i = 223;
  int x1i = (int)x0 + 1; if (x1i < 0) x1i = 0; if (x1i > 223) x1i = 223;
  int y1i = (int)y0 + 1; if (y1i < 0) y1i = 0; if (y1i > 223) y1i = 223;
  const float* im = x + ((long)n * 16 + c) * 50176;
  float v00 = im[y0i * 224 + x0i], v01 = im[y0i * 224 + x1i];
  float v10 = im[y1i * 224 + x0i], v11 = im[y1i * 224 + x1i];
  float val = v00 * (1.f - wx) * (1.f - wy) + v01 * wx * (1.f - wy) +
              v10 * (1.f - wx) * wy + v11 * wx * wy;
  out[i] = val * m[n];
}

// ---------------------------------------------------------------------------
extern "C" void kernel_launch(void* const* d_in, const int* in_sizes, int n_in,
                              void* d_out, int out_size, void* d_ws,
                              size_t ws_size, hipStream_t stream) {
  const float* x       = (const float*)d_in[0];
  const float* conv0_w = (const float*)d_in[1];
  // d_in[2] conv0_b: cancels in BN, unused
  const float* convs_w = (const float*)d_in[3];
  // d_in[4] convs_b: cancels in BN, unused
  const float* bn_g = (const float*)d_in[5];
  const float* bn_b = (const float*)d_in[6];
  const float* Wr   = (const float*)d_in[7];
  const float* br   = (const float*)d_in[8];
  const float* u0   = (const float*)d_in[9];
  const float* v0   = (const float*)d_in[10];
  float* out = (float*)d_out;
  float* ws  = (float*)d_ws;

  // ws layout (floats): total 24,783,616 (~94.6 MiB)
  float* bufB   = ws;                  // 24,780,800 (16,128,110,110)
  float* stats  = ws + 24780800L;      // 256
  float* mom    = stats + 256;         // 152 (pad 160)
  float* Wp     = mom + 160;           // 2048
  float* bp     = Wp + 2048;           // 128
  float* regb   = bp + 128;            // 112
  float* thetab = regb + 112;          // 96
  float* mb     = thetab + 96;         // 16

  // d_out scratch: tempAct = 2 images x (128,224,224) = 12,845,056 floats
  // (exactly out_size); bufC (<=5,750,272 floats) reuses d_out after stage 1.
  float* tempAct = out;
  float* bufC    = out;

  // ---- stage-0 BN stats analytically from x moments; fold into W', b' ----
  zero_kernel<<<2, 256, 0, stream>>>(stats, 416);  // stats + mom
  moment_kernel<<<784, 256, 0, stream>>>(x, mom);
  foldbn_kernel<<<1, 128, 0, stream>>>(conv0_w, mom, bn_g, bn_b, Wp, bp);

  // ---- stage 0+1 in 8 rounds of 2 images ----
  for (int r = 0; r < 8; ++r) {
    conv0act_kernel<<<dim3(49, 4, 2), 256, 0, stream>>>(x, Wp, bp, tempAct,
                                                        2 * r);
    conv3pool_kernel<<<dim3(49, 16, 2), 256, 0, stream>>>(
        tempAct, convs_w, bufB, 224, 110, 2 * r);
  }
  zero_kernel<<<1, 256, 0, stream>>>(stats, 256);
  stats_kernel<<<dim3(128, 16), 256, 0, stream>>>(bufB, stats, 12100);
  {
    long total = 16L * 128 * 12100;
    bnrelu_kernel<<<(int)((total + 255) / 256), 256, 0, stream>>>(
        bufB, stats, bn_g + 128, bn_b + 128, 12100, 1.f / (16.f * 12100.f),
        total);
  }

  // ---- stages 2..5: ping-pong bufB <-> bufC(d_out) ----
  const int Sins[4]  = {110, 53, 25, 11};
  const int Pouts[4] = {53, 25, 11, 4};
  for (int s = 0; s < 4; ++s) {
    float* ib = (s % 2 == 0) ? bufB : bufC;
    float* ob = (s % 2 == 0) ? bufC : bufB;
    int Sin = Sins[s], Pout = Pouts[s];
    int tiles = (Pout + 15) / 16;
    conv3pool_kernel<<<dim3(tiles * tiles, 16, 16), 256, 0, stream>>>(
        ib, convs_w + (long)(s + 1) * 128 * 128 * 9, ob, Sin, Pout, 0);
    zero_kernel<<<1, 256, 0, stream>>>(stats, 256);
    int P2 = Pout * Pout;
    stats_kernel<<<dim3(128, 16), 256, 0, stream>>>(ob, stats, P2);
    long total = 16L * 128 * P2;
    bnrelu_kernel<<<(int)((total + 255) / 256), 256, 0, stream>>>(
        ob, stats, bn_g + (s + 2) * 128, bn_b + (s + 2) * 128, P2,
        1.f / (16.f * P2), total);
  }

  // ---- tail: LRN -> GEMV -> spectral norm -> sample (overwrites d_out) ----
  lrn_kernel<<<16, 128, 0, stream>>>(bufB);
  gemv_kernel<<<16, 256, 0, stream>>>(bufB, Wr, br, regb);
  sn_kernel<<<1, 1, 0, stream>>>(regb, u0, v0, thetab, mb);
  sample_kernel<<<50176, 256, 0, stream>>>(x, thetab, mb, out);
}

// Round 4
// 8752.386 us; speedup vs baseline: 9.3802x; 3.2460x over previous
//
#include <hip/hip_runtime.h>
#include <math.h>

// ---------------------------------------------------------------------------
// SpatialTransformer forward, fp32 end-to-end.
// conv0(1x1)+BN+ReLU folded analytically (BN stats from 16x16 moment matrix),
// then 5x [conv3x3(valid)+maxpool3s2+BN+ReLU] -> LRN(128) -> GEMV(7x2048)
// -> spectral-norm scan -> affine_grid + grid_sample(reflect) * sigmoid(m).
// Conv biases cancel exactly in training-mode BN and are skipped.
// R4: conv3pool retiled to 15x15 pooled outputs / block = exactly one 2x2
// conv patch per thread (256 = 16x16 patches); pool loop fully unrolled so
// acc[] is never dynamically indexed (R2/R3 scratch-spill root cause).
// ---------------------------------------------------------------------------

#define CO_PB 8  // output channels per conv3pool block

// ---------------- util: zero a small region --------------------------------
__global__ void zero_kernel(float* __restrict__ p, int n) {
  int i = blockIdx.x * 256 + threadIdx.x;
  if (i < n) p[i] = 0.f;
}

// ---------------- moments of x: sums[16], upper-tri products[136] ----------
__global__ __launch_bounds__(256) void moment_kernel(
    const float* __restrict__ x, float* __restrict__ mom) {
  const int tid = threadIdx.x;
  int q = blockIdx.x * 256 + tid;  // 0..200703 quad index
  int n = q / 12544, pq = q - n * 12544;
  const float* xb = x + ((long)n * 16) * 50176 + pq * 4;
  float4 v4[16];
#pragma unroll
  for (int i = 0; i < 16; ++i) v4[i] = *(const float4*)(xb + (long)i * 50176);
  float accs[16];
  float accp[136];
#pragma unroll
  for (int i = 0; i < 16; ++i) accs[i] = 0.f;
#pragma unroll
  for (int k = 0; k < 136; ++k) accp[k] = 0.f;
#pragma unroll
  for (int p = 0; p < 4; ++p) {
    float v[16];
#pragma unroll
    for (int i = 0; i < 16; ++i)
      v[i] = (p == 0) ? v4[i].x : (p == 1) ? v4[i].y : (p == 2) ? v4[i].z : v4[i].w;
#pragma unroll
    for (int i = 0; i < 16; ++i) accs[i] += v[i];
    int k = 0;
#pragma unroll
    for (int i = 0; i < 16; ++i)
#pragma unroll
      for (int j = i; j < 16; ++j) { accp[k] += v[i] * v[j]; ++k; }
  }
  __shared__ float s_part[4][152];
  const int lane = tid & 63, wv = tid >> 6;
#pragma unroll
  for (int k = 0; k < 16; ++k) {
    float t = accs[k];
#pragma unroll
    for (int o = 32; o; o >>= 1) t += __shfl_down(t, o, 64);
    if (lane == 0) s_part[wv][k] = t;
  }
#pragma unroll
  for (int k = 0; k < 136; ++k) {
    float t = accp[k];
#pragma unroll
    for (int o = 32; o; o >>= 1) t += __shfl_down(t, o, 64);
    if (lane == 0) s_part[wv][16 + k] = t;
  }
  __syncthreads();
  if (tid < 152) {
    float t = s_part[0][tid] + s_part[1][tid] + s_part[2][tid] + s_part[3][tid];
    atomicAdd(&mom[tid], t);
  }
}

// ---------------- fold conv0 + BN into W' x + b' ---------------------------
__global__ void foldbn_kernel(const float* __restrict__ w0,
                              const float* __restrict__ mom,
                              const float* __restrict__ g,
                              const float* __restrict__ b,
                              float* __restrict__ Wp, float* __restrict__ bp) {
  int c = threadIdx.x;
  if (c >= 128) return;
  const float invN = 1.f / 802816.f;
  float w[16], m[16];
#pragma unroll
  for (int i = 0; i < 16; ++i) { w[i] = w0[c * 16 + i]; m[i] = mom[i] * invN; }
  float mu = 0.f;
#pragma unroll
  for (int i = 0; i < 16; ++i) mu += w[i] * m[i];
  float ey2 = 0.f;
  int k = 0;
#pragma unroll
  for (int i = 0; i < 16; ++i)
#pragma unroll
    for (int j = i; j < 16; ++j) {
      float Mij = mom[16 + k] * invN;
      ey2 += ((i == j) ? 1.f : 2.f) * w[i] * w[j] * Mij;
      ++k;
    }
  float var = ey2 - mu * mu;
  float al = g[c] * rsqrtf(var + 1e-5f);
#pragma unroll
  for (int i = 0; i < 16; ++i) Wp[c * 16 + i] = al * w[i];
  bp[c] = b[c] - al * mu;
}

// ---------------- stage 0 folded: act = relu(W' x + b'), 2 images ----------
__global__ __launch_bounds__(256) void conv0act_kernel(
    const float* __restrict__ x, const float* __restrict__ Wp,
    const float* __restrict__ bp, float* __restrict__ act, int n_base) {
  __shared__ float sw[512];
  __shared__ float sb[32];
  const int tid = threadIdx.x;
  const int co0 = blockIdx.y * 32;
  for (int e = tid; e < 512; e += 256) sw[e] = Wp[co0 * 16 + e];
  if (tid < 32) sb[tid] = bp[co0 + tid];
  __syncthreads();
  const int q = blockIdx.x * 256 + tid;  // 0..12543 quad within image
  const int nloc = blockIdx.z;
  const float* xb = x + ((long)(n_base + nloc) * 16) * 50176 + q * 4;
  float4 v4[16];
#pragma unroll
  for (int i = 0; i < 16; ++i) v4[i] = *(const float4*)(xb + (long)i * 50176);
  float* ob = act + ((long)nloc * 128) * 50176 + q * 4;
  for (int u = 0; u < 32; ++u) {
    float bb = sb[u];
    float4 a = make_float4(bb, bb, bb, bb);
#pragma unroll
    for (int i = 0; i < 16; ++i) {
      float w = sw[u * 16 + i];
      a.x += w * v4[i].x; a.y += w * v4[i].y;
      a.z += w * v4[i].z; a.w += w * v4[i].w;
    }
    a.x = fmaxf(a.x, 0.f); a.y = fmaxf(a.y, 0.f);
    a.z = fmaxf(a.z, 0.f); a.w = fmaxf(a.w, 0.f);
    *(float4*)(ob + (long)(co0 + u) * 50176) = a;
  }
}

// ---------------- per-channel BN statistics (sum, sumsq) -------------------
__global__ __launch_bounds__(256) void stats_kernel(
    const float* __restrict__ buf, float* __restrict__ stats, int P2) {
  const int c = blockIdx.x;
  const int n = blockIdx.y;
  const int tid = threadIdx.x;
  const float* b = buf + ((long)n * 128 + c) * P2;
  float s = 0.f, q = 0.f;
  for (int i = tid; i < P2; i += 256) {
    float v = b[i];
    s += v; q += v * v;
  }
  __shared__ float rs[256], rq[256];
  rs[tid] = s; rq[tid] = q;
  __syncthreads();
  for (int off = 128; off; off >>= 1) {
    if (tid < off) { rs[tid] += rs[tid + off]; rq[tid] += rq[tid + off]; }
    __syncthreads();
  }
  if (tid == 0) {
    atomicAdd(&stats[c], rs[0]);
    atomicAdd(&stats[128 + c], rq[0]);
  }
}

// ---------------- apply BN + ReLU in place ---------------------------------
__global__ __launch_bounds__(256) void bnrelu_kernel(
    float* __restrict__ buf, const float* __restrict__ stats,
    const float* __restrict__ g, const float* __restrict__ b,
    int P2, float invM, long total) {
  long i = (long)blockIdx.x * 256 + threadIdx.x;
  if (i >= total) return;
  int c = (int)((i / P2) & 127);
  float mu = stats[c] * invM;
  float var = stats[128 + c] * invM - mu * mu;
  float al = g[c] * rsqrtf(var + 1e-5f);
  float v = buf[i];
  buf[i] = fmaxf(al * (v - mu) + b[c], 0.f);
}

// ---------------- fused conv3x3(valid, no bias) + maxpool3s2 ---------------
// grid: x = tiles^2 (15x15 pooled tiles), y = 16 co-groups (CO_PB=8),
// z = images. One 2x2 conv patch per thread (16x16 patch grid). Weights via
// block-uniform scalar loads. LDS: 4ci x 34-row x stride-36 (19.6 KB).
__global__ __launch_bounds__(256, 4) void conv3pool_kernel(
    const float* __restrict__ in, const float* __restrict__ wt,
    float* __restrict__ out, int Sin, int Pout, int n_base) {
  const int tid = threadIdx.x;
  const int tilesX = (Pout + 14) / 15;
  const int ty = blockIdx.x / tilesX, tx = blockIdx.x - ty * tilesX;
  const int co0 = blockIdx.y * CO_PB;
  const int nloc = blockIdx.z;
  const int py0 = ty * 15, px0 = tx * 15;
  const int iy0 = py0 * 2, ix0 = px0 * 2;

  __shared__ float s_in[4 * 1224];  // 4 ci x (34 rows x stride 36)

  const int pi = tid >> 4, pj = tid & 15;  // this thread's 2x2 conv patch

  float acc[CO_PB][4];
#pragma unroll
  for (int u = 0; u < CO_PB; ++u)
#pragma unroll
    for (int k = 0; k < 4; ++k) acc[u][k] = 0.f;

  const long S2 = (long)Sin * Sin;
  const long inbase = ((long)nloc * 128) * S2;

  for (int ci0 = 0; ci0 < 128; ci0 += 4) {
    __syncthreads();  // previous iteration's s_in readers done
    for (int e = tid; e < 4 * 1156; e += 256) {
      int cil = e / 1156;
      int rem = e - cil * 1156;
      int r = rem / 34, cc = rem - r * 34;
      int gy = iy0 + r; if (gy > Sin - 1) gy = Sin - 1;
      int gx = ix0 + cc; if (gx > Sin - 1) gx = Sin - 1;
      s_in[cil * 1224 + r * 36 + cc] =
          in[inbase + (long)(ci0 + cil) * S2 + (long)gy * Sin + gx];
    }
    __syncthreads();
#pragma unroll
    for (int cil = 0; cil < 4; ++cil) {
      const float* ip = &s_in[cil * 1224] + (2 * pi) * 36 + 2 * pj;
      float iv[16];
#pragma unroll
      for (int r = 0; r < 4; ++r)
#pragma unroll
        for (int cc2 = 0; cc2 < 4; ++cc2)
          iv[r * 4 + cc2] = ip[r * 36 + cc2];
#pragma unroll
      for (int u = 0; u < CO_PB; ++u) {
        // block-uniform address -> compiler scalarizes to s_load (SGPRs)
        const float* wp = wt + ((long)(co0 + u) * 128 + (ci0 + cil)) * 9;
#pragma unroll
        for (int ky = 0; ky < 3; ++ky)
#pragma unroll
          for (int kx = 0; kx < 3; ++kx) {
            float w = wp[ky * 3 + kx];
            acc[u][0] += w * iv[ky * 4 + kx];
            acc[u][1] += w * iv[ky * 4 + kx + 1];
            acc[u][2] += w * iv[(ky + 1) * 4 + kx];
            acc[u][3] += w * iv[(ky + 1) * 4 + kx + 1];
          }
      }
    }
  }

  // pooling via LDS staging of the 32x32 conv tile (stride 33), per co.
  // FULLY UNROLLED so acc[] indices stay compile-time constants (R3 bug).
  float* s_conv = s_in;
  const int gpy = py0 + pi, gpx = px0 + pj;
  const bool wvalid = (pi < 15) && (pj < 15) && (gpy < Pout) && (gpx < Pout);
  float* cp = s_conv + (2 * pi) * 33 + 2 * pj;
  const float* rp = s_conv + (2 * pi) * 33 + 2 * pj;  // pool read base
#pragma unroll
  for (int u = 0; u < CO_PB; ++u) {
    __syncthreads();
    cp[0] = acc[u][0]; cp[1] = acc[u][1];
    cp[33] = acc[u][2]; cp[34] = acc[u][3];
    __syncthreads();
    if (wvalid) {
      float mx = rp[0];
#pragma unroll
      for (int dy = 0; dy < 3; ++dy)
#pragma unroll
        for (int dx = 0; dx < 3; ++dx)
          mx = fmaxf(mx, rp[dy * 33 + dx]);
      out[(((long)(n_base + nloc) * 128 + (co0 + u)) * Pout + gpy) * Pout + gpx] = mx;
    }
  }
}

// ---------------- LRN, size = 128 over the channel axis --------------------
__global__ __launch_bounds__(128) void lrn_kernel(float* __restrict__ buf) {
  const int n = blockIdx.x;
  const int c = threadIdx.x;
  __shared__ float sq[128];
  float* b = buf + (long)n * 2048;
  for (int p = 0; p < 16; ++p) {
    float v = b[c * 16 + p];
    sq[c] = v * v;
    __syncthreads();
    int lo = c - 64 < 0 ? 0 : c - 64;
    int hi = c + 63 > 127 ? 127 : c + 63;
    float win = 0.f;
    for (int j = lo; j <= hi; ++j) win += sq[j];
    b[c * 16 + p] = v * powf(1.f + (1e-4f / 128.f) * win, -0.75f);
    __syncthreads();
  }
}

// ---------------- regression head: reg = xs @ Wr.T + br --------------------
__global__ __launch_bounds__(256) void gemv_kernel(
    const float* __restrict__ xs, const float* __restrict__ Wr,
    const float* __restrict__ br, float* __restrict__ reg) {
  const int n = blockIdx.x;
  const int tid = threadIdx.x;
  float a[7] = {0.f, 0.f, 0.f, 0.f, 0.f, 0.f, 0.f};
  for (int e = tid; e < 2048; e += 256) {
    float v = xs[(long)n * 2048 + e];
#pragma unroll
    for (int j = 0; j < 7; ++j) a[j] += v * Wr[j * 2048 + e];
  }
  __shared__ float red[256];
  for (int j = 0; j < 7; ++j) {
    red[tid] = a[j];
    __syncthreads();
    for (int off = 128; off; off >>= 1) {
      if (tid < off) red[tid] += red[tid + off];
      __syncthreads();
    }
    if (tid == 0) reg[n * 7 + j] = red[0] + br[j];
    __syncthreads();
  }
}

// ---------------- spectral norm (sequential scan over batch) ---------------
__global__ void sn_kernel(const float* __restrict__ reg,
                          const float* __restrict__ u0g,
                          const float* __restrict__ v0g,
                          float* __restrict__ theta, float* __restrict__ m) {
  if (threadIdx.x != 0 || blockIdx.x != 0) return;
  float u[2] = {u0g[0], u0g[1]};
  float v[3] = {v0g[0], v0g[1], v0g[2]};
  for (int n = 0; n < 16; ++n) {
    const float* W = reg + n * 7;
    for (int it = 0; it < 4; ++it) {
      float v0n = W[0] * u[0] + W[3] * u[1];
      float v1n = W[1] * u[0] + W[4] * u[1];
      float v2n = W[2] * u[0] + W[5] * u[1];
      float nv = sqrtf(v0n * v0n + v1n * v1n + v2n * v2n);
      nv = fmaxf(nv, 1e-12f);
      v[0] = v0n / nv; v[1] = v1n / nv; v[2] = v2n / nv;
      float u0n = W[0] * v[0] + W[1] * v[1] + W[2] * v[2];
      float u1n = W[3] * v[0] + W[4] * v[1] + W[5] * v[2];
      float nu = sqrtf(u0n * u0n + u1n * u1n);
      nu = fmaxf(nu, 1e-12f);
      u[0] = u0n / nu; u[1] = u1n / nu;
    }
    float Wv0 = W[0] * v[0] + W[1] * v[1] + W[2] * v[2];
    float Wv1 = W[3] * v[0] + W[4] * v[1] + W[5] * v[2];
    float sigma = u[0] * Wv0 + u[1] * Wv1;
    for (int k = 0; k < 6; ++k) theta[n * 6 + k] = W[k] / sigma;
    m[n] = 1.f / (1.f + expf(-W[6]));
  }
}

// ---------------- affine grid + reflect grid_sample + mask scale -----------
__device__ __forceinline__ float reflectf(float x, float size) {
  x = fabsf(x + 0.5f);
  x = fmodf(x, 2.f * size);
  if (x > size) x = 2.f * size - x;
  x -= 0.5f;
  return fminf(fmaxf(x, 0.f), size - 1.f);
}

__global__ __launch_bounds__(256) void sample_kernel(
    const float* __restrict__ x, const float* __restrict__ theta,
    const float* __restrict__ m, float* __restrict__ out) {
  long i = (long)blockIdx.x * 256 + threadIdx.x;
  if (i >= 12845056L) return;
  int w = (int)(i % 224);
  long t = i / 224;
  int h = (int)(t % 224); t /= 224;
  int c = (int)(t % 16);
  int n = (int)(t / 16);
  const float* th = theta + n * 6;
  float xn = (2 * w + 1) * (1.f / 224.f) - 1.f;
  float yn = (2 * h + 1) * (1.f / 224.f) - 1.f;
  float gx = th[0] * xn + th[1] * yn + th[2];
  float gy = th[3] * xn + th[4] * yn + th[5];
  float ix = reflectf(((gx + 1.f) * 224.f - 1.f) * 0.5f, 224.f);
  float iy = reflectf(((gy + 1.f) * 224.f - 1.f) * 0.5f, 224.f);
  float x0 = floorf(ix), y0 = floorf(iy);
  float wx = ix - x0, wy = iy - y0;
  int x0i = (int)x0; if (x0i < 0) x0i = 0; if (x0i > 223) x0i = 223;
  int y0i = (int)y0; if (y0i < 0) y0i = 0; if (y0i > 223) y0i = 223;
  int x1i = (int)x0 + 1; if (x1i < 0) x1i = 0; if (x1i > 223) x1i = 223;
  int y1i = (int)y0 + 1; if (y1i < 0) y1i = 0; if (y1i > 223) y1i = 223;
  const float* im = x + ((long)n * 16 + c) * 50176;
  float v00 = im[y0i * 224 + x0i], v01 = im[y0i * 224 + x1i];
  float v10 = im[y1i * 224 + x0i], v11 = im[y1i * 224 + x1i];
  float val = v00 * (1.f - wx) * (1.f - wy) + v01 * wx * (1.f - wy) +
              v10 * (1.f - wx) * wy + v11 * wx * wy;
  out[i] = val * m[n];
}

// ---------------------------------------------------------------------------
extern "C" void kernel_launch(void* const* d_in, const int* in_sizes, int n_in,
                              void* d_out, int out_size, void* d_ws,
                              size_t ws_size, hipStream_t stream) {
  const float* x       = (const float*)d_in[0];
  const float* conv0_w = (const float*)d_in[1];
  // d_in[2] conv0_b: cancels in BN, unused
  const float* convs_w = (const float*)d_in[3];
  // d_in[4] convs_b: cancels in BN, unused
  const float* bn_g = (const float*)d_in[5];
  const float* bn_b = (const float*)d_in[6];
  const float* Wr   = (const float*)d_in[7];
  const float* br   = (const float*)d_in[8];
  const float* u0   = (const float*)d_in[9];
  const float* v0   = (const float*)d_in[10];
  float* out = (float*)d_out;
  float* ws  = (float*)d_ws;

  // ws layout (floats): total 24,783,616 (~94.6 MiB)
  float* bufB   = ws;                  // 24,780,800 (16,128,110,110)
  float* stats  = ws + 24780800L;      // 256
  float* mom    = stats + 256;         // 152 (pad 160)
  float* Wp     = mom + 160;           // 2048
  float* bp     = Wp + 2048;           // 128
  float* regb   = bp + 128;            // 112
  float* thetab = regb + 112;          // 96
  float* mb     = thetab + 96;         // 16

  // d_out scratch: tempAct = 2 images x (128,224,224) = 12,845,056 floats
  // (exactly out_size); bufC (<=5,750,272 floats) reuses d_out after stage 1.
  float* tempAct = out;
  float* bufC    = out;

  // ---- stage-0 BN stats analytically from x moments; fold into W', b' ----
  zero_kernel<<<2, 256, 0, stream>>>(stats, 416);  // stats + mom
  moment_kernel<<<784, 256, 0, stream>>>(x, mom);
  foldbn_kernel<<<1, 128, 0, stream>>>(conv0_w, mom, bn_g, bn_b, Wp, bp);

  // ---- stage 0+1 in 8 rounds of 2 images ----
  for (int r = 0; r < 8; ++r) {
    conv0act_kernel<<<dim3(49, 4, 2), 256, 0, stream>>>(x, Wp, bp, tempAct,
                                                        2 * r);
    conv3pool_kernel<<<dim3(64, 16, 2), 256, 0, stream>>>(
        tempAct, convs_w, bufB, 224, 110, 2 * r);
  }
  zero_kernel<<<1, 256, 0, stream>>>(stats, 256);
  stats_kernel<<<dim3(128, 16), 256, 0, stream>>>(bufB, stats, 12100);
  {
    long total = 16L * 128 * 12100;
    bnrelu_kernel<<<(int)((total + 255) / 256), 256, 0, stream>>>(
        bufB, stats, bn_g + 128, bn_b + 128, 12100, 1.f / (16.f * 12100.f),
        total);
  }

  // ---- stages 2..5: ping-pong bufB <-> bufC(d_out) ----
  const int Sins[4]  = {110, 53, 25, 11};
  const int Pouts[4] = {53, 25, 11, 4};
  for (int s = 0; s < 4; ++s) {
    float* ib = (s % 2 == 0) ? bufB : bufC;
    float* ob = (s % 2 == 0) ? bufC : bufB;
    int Sin = Sins[s], Pout = Pouts[s];
    int tiles = (Pout + 14) / 15;
    conv3pool_kernel<<<dim3(tiles * tiles, 16, 16), 256, 0, stream>>>(
        ib, convs_w + (long)(s + 1) * 128 * 128 * 9, ob, Sin, Pout, 0);
    zero_kernel<<<1, 256, 0, stream>>>(stats, 256);
    int P2 = Pout * Pout;
    stats_kernel<<<dim3(128, 16), 256, 0, stream>>>(ob, stats, P2);
    long total = 16L * 128 * P2;
    bnrelu_kernel<<<(int)((total + 255) / 256), 256, 0, stream>>>(
        ob, stats, bn_g + (s + 2) * 128, bn_b + (s + 2) * 128, P2,
        1.f / (16.f * P2), total);
  }

  // ---- tail: LRN -> GEMV -> spectral norm -> sample (overwrites d_out) ----
  lrn_kernel<<<16, 128, 0, stream>>>(bufB);
  gemv_kernel<<<16, 256, 0, stream>>>(bufB, Wr, br, regb);
  sn_kernel<<<1, 1, 0, stream>>>(regb, u0, v0, thetab, mb);
  sample_kernel<<<50176, 256, 0, stream>>>(x, thetab, mb, out);
}

// Round 5
// 8395.654 us; speedup vs baseline: 9.7788x; 1.0425x over previous
//
#include <hip/hip_runtime.h>
#include <math.h>

// ---------------------------------------------------------------------------
// SpatialTransformer forward, fp32 end-to-end.
// conv0(1x1)+BN+ReLU folded analytically (BN stats from 16x16 moment matrix),
// then 5x [conv3x3(valid)+maxpool3s2+BN+ReLU] -> LRN(128) -> GEMV(7x2048)
// -> spectral-norm scan -> affine_grid + grid_sample(reflect) * sigmoid(m).
// Conv biases cancel exactly in training-mode BN and are skipped.
// R5: conv3pool weights staged per-ci0-chunk into LDS (b128 broadcast reads)
// — R4's per-tap global loads were not scalarized and ate ~2/3 of issue BW.
// ---------------------------------------------------------------------------

#define CO_PB 8  // output channels per conv3pool block

// ---------------- util: zero a small region --------------------------------
__global__ void zero_kernel(float* __restrict__ p, int n) {
  int i = blockIdx.x * 256 + threadIdx.x;
  if (i < n) p[i] = 0.f;
}

// ---------------- moments of x: sums[16], upper-tri products[136] ----------
__global__ __launch_bounds__(256) void moment_kernel(
    const float* __restrict__ x, float* __restrict__ mom) {
  const int tid = threadIdx.x;
  int q = blockIdx.x * 256 + tid;  // 0..200703 quad index
  int n = q / 12544, pq = q - n * 12544;
  const float* xb = x + ((long)n * 16) * 50176 + pq * 4;
  float4 v4[16];
#pragma unroll
  for (int i = 0; i < 16; ++i) v4[i] = *(const float4*)(xb + (long)i * 50176);
  float accs[16];
  float accp[136];
#pragma unroll
  for (int i = 0; i < 16; ++i) accs[i] = 0.f;
#pragma unroll
  for (int k = 0; k < 136; ++k) accp[k] = 0.f;
#pragma unroll
  for (int p = 0; p < 4; ++p) {
    float v[16];
#pragma unroll
    for (int i = 0; i < 16; ++i)
      v[i] = (p == 0) ? v4[i].x : (p == 1) ? v4[i].y : (p == 2) ? v4[i].z : v4[i].w;
#pragma unroll
    for (int i = 0; i < 16; ++i) accs[i] += v[i];
    int k = 0;
#pragma unroll
    for (int i = 0; i < 16; ++i)
#pragma unroll
      for (int j = i; j < 16; ++j) { accp[k] += v[i] * v[j]; ++k; }
  }
  __shared__ float s_part[4][152];
  const int lane = tid & 63, wv = tid >> 6;
#pragma unroll
  for (int k = 0; k < 16; ++k) {
    float t = accs[k];
#pragma unroll
    for (int o = 32; o; o >>= 1) t += __shfl_down(t, o, 64);
    if (lane == 0) s_part[wv][k] = t;
  }
#pragma unroll
  for (int k = 0; k < 136; ++k) {
    float t = accp[k];
#pragma unroll
    for (int o = 32; o; o >>= 1) t += __shfl_down(t, o, 64);
    if (lane == 0) s_part[wv][16 + k] = t;
  }
  __syncthreads();
  if (tid < 152) {
    float t = s_part[0][tid] + s_part[1][tid] + s_part[2][tid] + s_part[3][tid];
    atomicAdd(&mom[tid], t);
  }
}

// ---------------- fold conv0 + BN into W' x + b' ---------------------------
__global__ void foldbn_kernel(const float* __restrict__ w0,
                              const float* __restrict__ mom,
                              const float* __restrict__ g,
                              const float* __restrict__ b,
                              float* __restrict__ Wp, float* __restrict__ bp) {
  int c = threadIdx.x;
  if (c >= 128) return;
  const float invN = 1.f / 802816.f;
  float w[16], m[16];
#pragma unroll
  for (int i = 0; i < 16; ++i) { w[i] = w0[c * 16 + i]; m[i] = mom[i] * invN; }
  float mu = 0.f;
#pragma unroll
  for (int i = 0; i < 16; ++i) mu += w[i] * m[i];
  float ey2 = 0.f;
  int k = 0;
#pragma unroll
  for (int i = 0; i < 16; ++i)
#pragma unroll
    for (int j = i; j < 16; ++j) {
      float Mij = mom[16 + k] * invN;
      ey2 += ((i == j) ? 1.f : 2.f) * w[i] * w[j] * Mij;
      ++k;
    }
  float var = ey2 - mu * mu;
  float al = g[c] * rsqrtf(var + 1e-5f);
#pragma unroll
  for (int i = 0; i < 16; ++i) Wp[c * 16 + i] = al * w[i];
  bp[c] = b[c] - al * mu;
}

// ---------------- stage 0 folded: act = relu(W' x + b'), 2 images ----------
__global__ __launch_bounds__(256) void conv0act_kernel(
    const float* __restrict__ x, const float* __restrict__ Wp,
    const float* __restrict__ bp, float* __restrict__ act, int n_base) {
  __shared__ float sw[512];
  __shared__ float sb[32];
  const int tid = threadIdx.x;
  const int co0 = blockIdx.y * 32;
  for (int e = tid; e < 512; e += 256) sw[e] = Wp[co0 * 16 + e];
  if (tid < 32) sb[tid] = bp[co0 + tid];
  __syncthreads();
  const int q = blockIdx.x * 256 + tid;  // 0..12543 quad within image
  const int nloc = blockIdx.z;
  const float* xb = x + ((long)(n_base + nloc) * 16) * 50176 + q * 4;
  float4 v4[16];
#pragma unroll
  for (int i = 0; i < 16; ++i) v4[i] = *(const float4*)(xb + (long)i * 50176);
  float* ob = act + ((long)nloc * 128) * 50176 + q * 4;
  for (int u = 0; u < 32; ++u) {
    float bb = sb[u];
    float4 a = make_float4(bb, bb, bb, bb);
#pragma unroll
    for (int i = 0; i < 16; ++i) {
      float w = sw[u * 16 + i];
      a.x += w * v4[i].x; a.y += w * v4[i].y;
      a.z += w * v4[i].z; a.w += w * v4[i].w;
    }
    a.x = fmaxf(a.x, 0.f); a.y = fmaxf(a.y, 0.f);
    a.z = fmaxf(a.z, 0.f); a.w = fmaxf(a.w, 0.f);
    *(float4*)(ob + (long)(co0 + u) * 50176) = a;
  }
}

// ---------------- per-channel BN statistics (sum, sumsq) -------------------
__global__ __launch_bounds__(256) void stats_kernel(
    const float* __restrict__ buf, float* __restrict__ stats, int P2) {
  const int c = blockIdx.x;
  const int n = blockIdx.y;
  const int tid = threadIdx.x;
  const float* b = buf + ((long)n * 128 + c) * P2;
  float s = 0.f, q = 0.f;
  for (int i = tid; i < P2; i += 256) {
    float v = b[i];
    s += v; q += v * v;
  }
  __shared__ float rs[256], rq[256];
  rs[tid] = s; rq[tid] = q;
  __syncthreads();
  for (int off = 128; off; off >>= 1) {
    if (tid < off) { rs[tid] += rs[tid + off]; rq[tid] += rq[tid + off]; }
    __syncthreads();
  }
  if (tid == 0) {
    atomicAdd(&stats[c], rs[0]);
    atomicAdd(&stats[128 + c], rq[0]);
  }
}

// ---------------- apply BN + ReLU in place ---------------------------------
__global__ __launch_bounds__(256) void bnrelu_kernel(
    float* __restrict__ buf, const float* __restrict__ stats,
    const float* __restrict__ g, const float* __restrict__ b,
    int P2, float invM, long total) {
  long i = (long)blockIdx.x * 256 + threadIdx.x;
  if (i >= total) return;
  int c = (int)((i / P2) & 127);
  float mu = stats[c] * invM;
  float var = stats[128 + c] * invM - mu * mu;
  float al = g[c] * rsqrtf(var + 1e-5f);
  float v = buf[i];
  buf[i] = fmaxf(al * (v - mu) + b[c], 0.f);
}

// ---------------- fused conv3x3(valid, no bias) + maxpool3s2 ---------------
// grid: x = tiles^2 (15x15 pooled tiles), y = 16 co-groups (CO_PB=8),
// z = images. One 2x2 conv patch per thread (16x16 patch grid). Weights for
// the current 4-ci chunk staged in LDS (padded to 12 -> b128 broadcast
// reads); input tile 4ci x 34 rows x stride 36.
__global__ __launch_bounds__(256, 4) void conv3pool_kernel(
    const float* __restrict__ in, const float* __restrict__ wt,
    float* __restrict__ out, int Sin, int Pout, int n_base) {
  const int tid = threadIdx.x;
  const int tilesX = (Pout + 14) / 15;
  const int ty = blockIdx.x / tilesX, tx = blockIdx.x - ty * tilesX;
  const int co0 = blockIdx.y * CO_PB;
  const int nloc = blockIdx.z;
  const int py0 = ty * 15, px0 = tx * 15;
  const int iy0 = py0 * 2, ix0 = px0 * 2;

  __shared__ float s_in[4 * 1224];                 // 4 ci x (34 x stride 36)
  __shared__ __align__(16) float s_wt[4][CO_PB][12];  // chunk weights, padded

  const int pi = tid >> 4, pj = tid & 15;  // this thread's 2x2 conv patch

  float acc[CO_PB][4];
#pragma unroll
  for (int u = 0; u < CO_PB; ++u)
#pragma unroll
    for (int k = 0; k < 4; ++k) acc[u][k] = 0.f;

  const long S2 = (long)Sin * Sin;
  const long inbase = ((long)nloc * 128) * S2;

  for (int ci0 = 0; ci0 < 128; ci0 += 4) {
    __syncthreads();  // previous iteration's s_in/s_wt readers done
    for (int e = tid; e < 4 * 1156; e += 256) {
      int cil = e / 1156;
      int rem = e - cil * 1156;
      int r = rem / 34, cc = rem - r * 34;
      int gy = iy0 + r; if (gy > Sin - 1) gy = Sin - 1;
      int gx = ix0 + cc; if (gx > Sin - 1) gx = Sin - 1;
      s_in[cil * 1224 + r * 36 + cc] =
          in[inbase + (long)(ci0 + cil) * S2 + (long)gy * Sin + gx];
    }
    for (int e = tid; e < 288; e += 256) {
      int cil = e / 72, rem = e - cil * 72;
      int u = rem / 9, t = rem - u * 9;
      s_wt[cil][u][t] = wt[((long)(co0 + u) * 128 + (ci0 + cil)) * 9 + t];
    }
    __syncthreads();
#pragma unroll
    for (int cil = 0; cil < 4; ++cil) {
      const float* ip = &s_in[cil * 1224] + (2 * pi) * 36 + 2 * pj;
      float iv[16];
#pragma unroll
      for (int r = 0; r < 4; ++r)
#pragma unroll
        for (int cc2 = 0; cc2 < 4; ++cc2)
          iv[r * 4 + cc2] = ip[r * 36 + cc2];
#pragma unroll
      for (int u = 0; u < CO_PB; ++u) {
        const float4* wq = (const float4*)&s_wt[cil][u][0];
        float4 w0 = wq[0], w1 = wq[1], w2 = wq[2];
        float wv[9] = {w0.x, w0.y, w0.z, w0.w, w1.x, w1.y, w1.z, w1.w, w2.x};
#pragma unroll
        for (int ky = 0; ky < 3; ++ky)
#pragma unroll
          for (int kx = 0; kx < 3; ++kx) {
            float w = wv[ky * 3 + kx];
            acc[u][0] += w * iv[ky * 4 + kx];
            acc[u][1] += w * iv[ky * 4 + kx + 1];
            acc[u][2] += w * iv[(ky + 1) * 4 + kx];
            acc[u][3] += w * iv[(ky + 1) * 4 + kx + 1];
          }
      }
    }
  }

  // pooling via LDS staging of the 32x32 conv tile (stride 33), per co.
  // FULLY UNROLLED so acc[] indices stay compile-time constants.
  float* s_conv = s_in;
  const int gpy = py0 + pi, gpx = px0 + pj;
  const bool wvalid = (pi < 15) && (pj < 15) && (gpy < Pout) && (gpx < Pout);
  float* cp = s_conv + (2 * pi) * 33 + 2 * pj;
  const float* rp = s_conv + (2 * pi) * 33 + 2 * pj;  // pool read base
#pragma unroll
  for (int u = 0; u < CO_PB; ++u) {
    __syncthreads();
    cp[0] = acc[u][0]; cp[1] = acc[u][1];
    cp[33] = acc[u][2]; cp[34] = acc[u][3];
    __syncthreads();
    if (wvalid) {
      float mx = rp[0];
#pragma unroll
      for (int dy = 0; dy < 3; ++dy)
#pragma unroll
        for (int dx = 0; dx < 3; ++dx)
          mx = fmaxf(mx, rp[dy * 33 + dx]);
      out[(((long)(n_base + nloc) * 128 + (co0 + u)) * Pout + gpy) * Pout + gpx] = mx;
    }
  }
}

// ---------------- LRN, size = 128 over the channel axis --------------------
__global__ __launch_bounds__(128) void lrn_kernel(float* __restrict__ buf) {
  const int n = blockIdx.x;
  const int c = threadIdx.x;
  __shared__ float sq[128];
  float* b = buf + (long)n * 2048;
  for (int p = 0; p < 16; ++p) {
    float v = b[c * 16 + p];
    sq[c] = v * v;
    __syncthreads();
    int lo = c - 64 < 0 ? 0 : c - 64;
    int hi = c + 63 > 127 ? 127 : c + 63;
    float win = 0.f;
    for (int j = lo; j <= hi; ++j) win += sq[j];
    b[c * 16 + p] = v * powf(1.f + (1e-4f / 128.f) * win, -0.75f);
    __syncthreads();
  }
}

// ---------------- regression head: reg = xs @ Wr.T + br --------------------
__global__ __launch_bounds__(256) void gemv_kernel(
    const float* __restrict__ xs, const float* __restrict__ Wr,
    const float* __restrict__ br, float* __restrict__ reg) {
  const int n = blockIdx.x;
  const int tid = threadIdx.x;
  float a[7] = {0.f, 0.f, 0.f, 0.f, 0.f, 0.f, 0.f};
  for (int e = tid; e < 2048; e += 256) {
    float v = xs[(long)n * 2048 + e];
#pragma unroll
    for (int j = 0; j < 7; ++j) a[j] += v * Wr[j * 2048 + e];
  }
  __shared__ float red[256];
  for (int j = 0; j < 7; ++j) {
    red[tid] = a[j];
    __syncthreads();
    for (int off = 128; off; off >>= 1) {
      if (tid < off) red[tid] += red[tid + off];
      __syncthreads();
    }
    if (tid == 0) reg[n * 7 + j] = red[0] + br[j];
    __syncthreads();
  }
}

// ---------------- spectral norm (sequential scan over batch) ---------------
__global__ void sn_kernel(const float* __restrict__ reg,
                          const float* __restrict__ u0g,
                          const float* __restrict__ v0g,
                          float* __restrict__ theta, float* __restrict__ m) {
  if (threadIdx.x != 0 || blockIdx.x != 0) return;
  float u[2] = {u0g[0], u0g[1]};
  float v[3] = {v0g[0], v0g[1], v0g[2]};
  for (int n = 0; n < 16; ++n) {
    const float* W = reg + n * 7;
    for (int it = 0; it < 4; ++it) {
      float v0n = W[0] * u[0] + W[3] * u[1];
      float v1n = W[1] * u[0] + W[4] * u[1];
      float v2n = W[2] * u[0] + W[5] * u[1];
      float nv = sqrtf(v0n * v0n + v1n * v1n + v2n * v2n);
      nv = fmaxf(nv, 1e-12f);
      v[0] = v0n / nv; v[1] = v1n / nv; v[2] = v2n / nv;
      float u0n = W[0] * v[0] + W[1] * v[1] + W[2] * v[2];
      float u1n = W[3] * v[0] + W[4] * v[1] + W[5] * v[2];
      float nu = sqrtf(u0n * u0n + u1n * u1n);
      nu = fmaxf(nu, 1e-12f);
      u[0] = u0n / nu; u[1] = u1n / nu;
    }
    float Wv0 = W[0] * v[0] + W[1] * v[1] + W[2] * v[2];
    float Wv1 = W[3] * v[0] + W[4] * v[1] + W[5] * v[2];
    float sigma = u[0] * Wv0 + u[1] * Wv1;
    for (int k = 0; k < 6; ++k) theta[n * 6 + k] = W[k] / sigma;
    m[n] = 1.f / (1.f + expf(-W[6]));
  }
}

// ---------------- affine grid + reflect grid_sample + mask scale -----------
__device__ __forceinline__ float reflectf(float x, float size) {
  x = fabsf(x + 0.5f);
  x = fmodf(x, 2.f * size);
  if (x > size) x = 2.f * size - x;
  x -= 0.5f;
  return fminf(fmaxf(x, 0.f), size - 1.f);
}

__global__ __launch_bounds__(256) void sample_kernel(
    const float* __restrict__ x, const float* __restrict__ theta,
    const float* __restrict__ m, float* __restrict__ out) {
  long i = (long)blockIdx.x * 256 + threadIdx.x;
  if (i >= 12845056L) return;
  int w = (int)(i % 224);
  long t = i / 224;
  int h = (int)(t % 224); t /= 224;
  int c = (int)(t % 16);
  int n = (int)(t / 16);
  const float* th = theta + n * 6;
  float xn = (2 * w + 1) * (1.f / 224.f) - 1.f;
  float yn = (2 * h + 1) * (1.f / 224.f) - 1.f;
  float gx = th[0] * xn + th[1] * yn + th[2];
  float gy = th[3] * xn + th[4] * yn + th[5];
  float ix = reflectf(((gx + 1.f) * 224.f - 1.f) * 0.5f, 224.f);
  float iy = reflectf(((gy + 1.f) * 224.f - 1.f) * 0.5f, 224.f);
  float x0 = floorf(ix), y0 = floorf(iy);
  float wx = ix - x0, wy = iy - y0;
  int x0i = (int)x0; if (x0i < 0) x0i = 0; if (x0i > 223) x0i = 223;
  int y0i = (int)y0; if (y0i < 0) y0i = 0; if (y0i > 223) y0i = 223;
  int x1i = (int)x0 + 1; if (x1i < 0) x1i = 0; if (x1i > 223) x1i = 223;
  int y1i = (int)y0 + 1; if (y1i < 0) y1i = 0; if (y1i > 223) y1i = 223;
  const float* im = x + ((long)n * 16 + c) * 50176;
  float v00 = im[y0i * 224 + x0i], v01 = im[y0i * 224 + x1i];
  float v10 = im[y1i * 224 + x0i], v11 = im[y1i * 224 + x1i];
  float val = v00 * (1.f - wx) * (1.f - wy) + v01 * wx * (1.f - wy) +
              v10 * (1.f - wx) * wy + v11 * wx * wy;
  out[i] = val * m[n];
}

// ---------------------------------------------------------------------------
extern "C" void kernel_launch(void* const* d_in, const int* in_sizes, int n_in,
                              void* d_out, int out_size, void* d_ws,
                              size_t ws_size, hipStream_t stream) {
  const float* x       = (const float*)d_in[0];
  const float* conv0_w = (const float*)d_in[1];
  // d_in[2] conv0_b: cancels in BN, unused
  const float* convs_w = (const float*)d_in[3];
  // d_in[4] convs_b: cancels in BN, unused
  const float* bn_g = (const float*)d_in[5];
  const float* bn_b = (const float*)d_in[6];
  const float* Wr   = (const float*)d_in[7];
  const float* br   = (const float*)d_in[8];
  const float* u0   = (const float*)d_in[9];
  const float* v0   = (const float*)d_in[10];
  float* out = (float*)d_out;
  float* ws  = (float*)d_ws;

  // ws layout (floats): total 24,783,616 (~94.6 MiB)
  float* bufB   = ws;                  // 24,780,800 (16,128,110,110)
  float* stats  = ws + 24780800L;      // 256
  float* mom    = stats + 256;         // 152 (pad 160)
  float* Wp     = mom + 160;           // 2048
  float* bp     = Wp + 2048;           // 128
  float* regb   = bp + 128;            // 112
  float* thetab = regb + 112;          // 96
  float* mb     = thetab + 96;         // 16

  // d_out scratch: tempAct = 2 images x (128,224,224) = 12,845,056 floats
  // (exactly out_size); bufC (<=5,750,272 floats) reuses d_out after stage 1.
  float* tempAct = out;
  float* bufC    = out;

  // ---- stage-0 BN stats analytically from x moments; fold into W', b' ----
  zero_kernel<<<2, 256, 0, stream>>>(stats, 416);  // stats + mom
  moment_kernel<<<784, 256, 0, stream>>>(x, mom);
  foldbn_kernel<<<1, 128, 0, stream>>>(conv0_w, mom, bn_g, bn_b, Wp, bp);

  // ---- stage 0+1 in 8 rounds of 2 images ----
  for (int r = 0; r < 8; ++r) {
    conv0act_kernel<<<dim3(49, 4, 2), 256, 0, stream>>>(x, Wp, bp, tempAct,
                                                        2 * r);
    conv3pool_kernel<<<dim3(64, 16, 2), 256, 0, stream>>>(
        tempAct, convs_w, bufB, 224, 110, 2 * r);
  }
  zero_kernel<<<1, 256, 0, stream>>>(stats, 256);
  stats_kernel<<<dim3(128, 16), 256, 0, stream>>>(bufB, stats, 12100);
  {
    long total = 16L * 128 * 12100;
    bnrelu_kernel<<<(int)((total + 255) / 256), 256, 0, stream>>>(
        bufB, stats, bn_g + 128, bn_b + 128, 12100, 1.f / (16.f * 12100.f),
        total);
  }

  // ---- stages 2..5: ping-pong bufB <-> bufC(d_out) ----
  const int Sins[4]  = {110, 53, 25, 11};
  const int Pouts[4] = {53, 25, 11, 4};
  for (int s = 0; s < 4; ++s) {
    float* ib = (s % 2 == 0) ? bufB : bufC;
    float* ob = (s % 2 == 0) ? bufC : bufB;
    int Sin = Sins[s], Pout = Pouts[s];
    int tiles = (Pout + 14) / 15;
    conv3pool_kernel<<<dim3(tiles * tiles, 16, 16), 256, 0, stream>>>(
        ib, convs_w + (long)(s + 1) * 128 * 128 * 9, ob, Sin, Pout, 0);
    zero_kernel<<<1, 256, 0, stream>>>(stats, 256);
    int P2 = Pout * Pout;
    stats_kernel<<<dim3(128, 16), 256, 0, stream>>>(ob, stats, P2);
    long total = 16L * 128 * P2;
    bnrelu_kernel<<<(int)((total + 255) / 256), 256, 0, stream>>>(
        ob, stats, bn_g + (s + 2) * 128, bn_b + (s + 2) * 128, P2,
        1.f / (16.f * P2), total);
  }

  // ---- tail: LRN -> GEMV -> spectral norm -> sample (overwrites d_out) ----
  lrn_kernel<<<16, 128, 0, stream>>>(bufB);
  gemv_kernel<<<16, 256, 0, stream>>>(bufB, Wr, br, regb);
  sn_kernel<<<1, 1, 0, stream>>>(regb, u0, v0, thetab, mb);
  sample_kernel<<<50176, 256, 0, stream>>>(x, thetab, mb, out);
}